// Round 5
// baseline (295.716 us; speedup 1.0000x reference)
//
#include <hip/hip_runtime.h>

#define NN 4096
#define CC 32
#define TT 12
#define BB 4
#define BT 48          // BB*TT
#define NC 1536        // BT*CC
#define MAXD 192       // mean degree ~82; P(deg>192) astronomically small
#define FWW 512        // features per wave (16B/lane); chunk working set 4MB
#define NCH 3          // NC / FWW
#define STP 36         // k_trans LDS row stride (ushorts)

typedef float f32x4 __attribute__((ext_vector_type(4)));
typedef short short8 __attribute__((ext_vector_type(8)));

__device__ __forceinline__ float bf2f(unsigned short h) {
  return __uint_as_float(((unsigned int)h) << 16);
}
__device__ __forceinline__ unsigned short f2bf(float f) {
  unsigned int u = __float_as_uint(f);
  return (unsigned short)((u + 0x7FFFu + ((u >> 16) & 1u)) >> 16);  // RNE
}
__device__ __forceinline__ float blo(unsigned int w) { return __uint_as_float(w << 16); }
__device__ __forceinline__ float bhi(unsigned int w) { return __uint_as_float(w & 0xFFFF0000u); }

// dtype sniff on W (uniform scalar loop, deterministic): bf16 halfwords have
// plausible exponent fields; fp32 low mantissa halfwords are ~uniform.
__device__ __forceinline__ int sniff_bf16(const void* w) {
  const unsigned int* p = (const unsigned int*)w;
  int hits = 0;
  #pragma unroll 8
  for (int i = 0; i < 256; ++i) {
    unsigned int e = (p[i] >> 7) & 0xFFu;
    hits += (e >= 90u && e <= 141u) ? 1 : 0;
  }
  return hits >= 150;
}

// ---- adjacency compaction into edges[].x + degree + d^-1/2 (sniffs dtype itself)
__global__ __launch_bounds__(256) void k_build(const void* __restrict__ adjv,
                                               const void* __restrict__ wgtv,
                                               uint2* __restrict__ edges,
                                               int* __restrict__ deg, float* __restrict__ dis) {
  int bf16 = sniff_bf16(wgtv);
  __shared__ int cnt;
  int m = blockIdx.x;
  if (threadIdx.x == 0) cnt = 0;
  __syncthreads();
  unsigned int* ecol = (unsigned int*)(edges + m * MAXD);
  if (bf16) {
    const uint4* row = (const uint4*)((const unsigned short*)adjv + (size_t)m * NN);
    for (int i = threadIdx.x; i < NN / 8; i += 256) {
      uint4 v = row[i];
      unsigned int ws[4] = {v.x, v.y, v.z, v.w};
      #pragma unroll
      for (int k = 0; k < 4; ++k) {
        if (ws[k] & 0xFFFFu) {
          int p = atomicAdd(&cnt, 1);
          if (p < MAXD) ecol[p * 2] = (unsigned int)(i * 8 + k * 2);
        }
        if (ws[k] >> 16) {
          int p = atomicAdd(&cnt, 1);
          if (p < MAXD) ecol[p * 2] = (unsigned int)(i * 8 + k * 2 + 1);
        }
      }
    }
  } else {
    const uint4* row = (const uint4*)((const float*)adjv + (size_t)m * NN);
    for (int i = threadIdx.x; i < NN / 4; i += 256) {
      uint4 v = row[i];
      unsigned int ws[4] = {v.x, v.y, v.z, v.w};
      #pragma unroll
      for (int k = 0; k < 4; ++k) {
        if (ws[k] != 0) {
          int p = atomicAdd(&cnt, 1);
          if (p < MAXD) ecol[p * 2] = (unsigned int)(i * 4 + k);
        }
      }
    }
  }
  __syncthreads();
  if (threadIdx.x == 0) {
    int d = cnt < MAXD ? cnt : MAXD;
    deg[m] = d;
    dis[m] = d > 0 ? (float)(1.0 / sqrt((double)d)) : 0.0f;
  }
}

// ---- edges[].y = dis[col]; pad edge list to multiple of 8 with {m, 0} dummies;
// deg[m] <- padded count (loop bound for gathers).
__global__ __launch_bounds__(192) void k_wt(uint2* __restrict__ edges,
                                            int* __restrict__ deg,
                                            const float* __restrict__ dis) {
  int m = blockIdx.x;
  int j = threadIdx.x;
  int d = deg[m];
  int dp = (d + 7) & ~7;
  if (j < d) {
    unsigned int* e = (unsigned int*)(edges + m * MAXD + j);
    e[1] = __float_as_uint(dis[e[0]]);
  } else if (j < dp) {
    edges[m * MAXD + j] = make_uint2((unsigned int)m, 0u);  // 0.0f weight
  }
  if (j == 0) deg[m] = dp;
}

// ---- x[b][c][n][t] -> H[n][bt][c] (bf16) via LDS transpose; coalesced both sides.
// Grid 256: b = bid>>6, n0 = (bid&63)*64. LDS tile sT[j=nl*12+t][c], stride 36.
__global__ __launch_bounds__(256) void k_trans(const void* __restrict__ xv,
                                               const void* __restrict__ wgtv,
                                               unsigned short* __restrict__ H) {
  __shared__ unsigned short sT[768 * STP];
  int bf16 = sniff_bf16(wgtv);
  int b = blockIdx.x >> 6;
  int n0 = (blockIdx.x & 63) * 64;
  int c = threadIdx.x >> 3;        // 32 c-groups
  int l8 = threadIdx.x & 7;
  size_t base = ((size_t)(b * CC + c) * NN + n0) * TT;   // elems
  #pragma unroll
  for (int it = 0; it < 24; ++it) {
    int j0 = l8 * 4 + it * 32;
    ushort4 v;
    if (bf16) {
      v = *(const ushort4*)((const unsigned short*)xv + base + j0);
    } else {
      float4 f = *(const float4*)((const float*)xv + base + j0);
      v.x = f2bf(f.x); v.y = f2bf(f.y); v.z = f2bf(f.z); v.w = f2bf(f.w);
    }
    sT[(j0 + 0) * STP + c] = v.x;
    sT[(j0 + 1) * STP + c] = v.y;
    sT[(j0 + 2) * STP + c] = v.z;
    sT[(j0 + 3) * STP + c] = v.w;
  }
  __syncthreads();
  // store: p = nl*12+t enumerates 768 runs; 8 lanes cover 32 c (8B each)
  int inner = threadIdx.x & 7;
  #pragma unroll
  for (int k = 0; k < 24; ++k) {
    int p = (threadIdx.x >> 3) + 32 * k;
    int nl = p / TT, t = p - nl * TT;
    ushort4 v = *(const ushort4*)&sT[p * STP + inner * 4];
    size_t off = ((size_t)(n0 + nl) * BT + b * TT + t) * CC + inner * 4;
    *(ushort4*)(H + off) = v;
  }
}

// ---- gather1: T1[m,q] = H[m,q] - dis[m]*sum_e dis[col]*H[col,q]
// grid (NN/4, NCH); wave wid owns node bx*4+wid; 16B/lane covers 512 features.
__global__ __launch_bounds__(256) void k_gather1(const unsigned short* __restrict__ H,
                                                 const uint2* __restrict__ edges,
                                                 const int* __restrict__ deg,
                                                 const float* __restrict__ dis,
                                                 unsigned short* __restrict__ T1) {
  int wid = __builtin_amdgcn_readfirstlane(threadIdx.x >> 6);
  int lane = threadIdx.x & 63;
  int m = blockIdx.x * 4 + wid;
  int d = deg[m];                       // padded to x8
  float dm = dis[m];
  const uint2* ep = edges + m * MAXD;
  int fo = blockIdx.y * FWW + lane * 8;
  const unsigned short* Hf = H + fo;
  float a0 = 0.f, a1 = 0.f, a2 = 0.f, a3 = 0.f, a4 = 0.f, a5 = 0.f, a6 = 0.f, a7 = 0.f;
  #pragma unroll 8
  for (int e = 0; e < d; ++e) {
    uint2 ew = ep[e];                   // wave-uniform -> batched s_load
    int cc = (int)ew.x;
    float w = __uint_as_float(ew.y);
    uint4 hv = *(const uint4*)(Hf + cc * NC);
    a0 = fmaf(w, blo(hv.x), a0); a1 = fmaf(w, bhi(hv.x), a1);
    a2 = fmaf(w, blo(hv.y), a2); a3 = fmaf(w, bhi(hv.y), a3);
    a4 = fmaf(w, blo(hv.z), a4); a5 = fmaf(w, bhi(hv.z), a5);
    a6 = fmaf(w, blo(hv.w), a6); a7 = fmaf(w, bhi(hv.w), a7);
  }
  uint4 hm = *(const uint4*)(Hf + m * NC);
  ushort4 o0, o1;
  o0.x = f2bf(blo(hm.x) - dm * a0); o0.y = f2bf(bhi(hm.x) - dm * a1);
  o0.z = f2bf(blo(hm.y) - dm * a2); o0.w = f2bf(bhi(hm.y) - dm * a3);
  o1.x = f2bf(blo(hm.z) - dm * a4); o1.y = f2bf(bhi(hm.z) - dm * a5);
  o1.z = f2bf(blo(hm.w) - dm * a6); o1.w = f2bf(bhi(hm.w) - dm * a7);
  unsigned short* op = T1 + (size_t)m * NC + fo;
  *(ushort4*)op = o0;
  *(ushort4*)(op + 4) = o1;
}

// ---- gather2: T2[m,q] = 2*T1[m,q] - 2*dm*sum_e dis[col]*T1[col,q] - H[m,q]
__global__ __launch_bounds__(256) void k_gather2(const unsigned short* __restrict__ H,
                                                 const unsigned short* __restrict__ T1,
                                                 const uint2* __restrict__ edges,
                                                 const int* __restrict__ deg,
                                                 const float* __restrict__ dis,
                                                 unsigned short* __restrict__ T2) {
  int wid = __builtin_amdgcn_readfirstlane(threadIdx.x >> 6);
  int lane = threadIdx.x & 63;
  int m = blockIdx.x * 4 + wid;
  int d = deg[m];
  float dm = dis[m];
  const uint2* ep = edges + m * MAXD;
  int fo = blockIdx.y * FWW + lane * 8;
  const unsigned short* Tf = T1 + fo;
  float a0 = 0.f, a1 = 0.f, a2 = 0.f, a3 = 0.f, a4 = 0.f, a5 = 0.f, a6 = 0.f, a7 = 0.f;
  #pragma unroll 8
  for (int e = 0; e < d; ++e) {
    uint2 ew = ep[e];
    int cc = (int)ew.x;
    float w = __uint_as_float(ew.y);
    uint4 hv = *(const uint4*)(Tf + cc * NC);
    a0 = fmaf(w, blo(hv.x), a0); a1 = fmaf(w, bhi(hv.x), a1);
    a2 = fmaf(w, blo(hv.y), a2); a3 = fmaf(w, bhi(hv.y), a3);
    a4 = fmaf(w, blo(hv.z), a4); a5 = fmaf(w, bhi(hv.z), a5);
    a6 = fmaf(w, blo(hv.w), a6); a7 = fmaf(w, bhi(hv.w), a7);
  }
  uint4 tm = *(const uint4*)(Tf + m * NC);
  uint4 hm = *(const uint4*)(H + (size_t)m * NC + fo);
  float td = 2.f * dm;
  ushort4 o0, o1;
  o0.x = f2bf(2.f * blo(tm.x) - td * a0 - blo(hm.x));
  o0.y = f2bf(2.f * bhi(tm.x) - td * a1 - bhi(hm.x));
  o0.z = f2bf(2.f * blo(tm.y) - td * a2 - blo(hm.y));
  o0.w = f2bf(2.f * bhi(tm.y) - td * a3 - bhi(hm.y));
  o1.x = f2bf(2.f * blo(tm.z) - td * a4 - blo(hm.z));
  o1.y = f2bf(2.f * bhi(tm.z) - td * a5 - bhi(hm.z));
  o1.z = f2bf(2.f * blo(tm.w) - td * a6 - blo(hm.w));
  o1.w = f2bf(2.f * bhi(tm.w) - td * a7 - bhi(hm.w));
  unsigned short* op = T2 + (size_t)m * NC + fo;
  *(ushort4*)op = o0;
  *(ushort4*)(op + 4) = o1;
}

// ---- MFMA channel mix with LDS-transposed coalesced stores (sniffs dtype).
#define SOP 33
__global__ __launch_bounds__(256) void k_mix(const unsigned short* __restrict__ H,
                                             const unsigned short* __restrict__ T1,
                                             const unsigned short* __restrict__ T2,
                                             const void* __restrict__ wgtv,
                                             const void* __restrict__ biasv,
                                             void* __restrict__ outv) {
  int bf16 = sniff_bf16(wgtv);
  __shared__ __align__(16) float sOut[192 * SOP];
  int wid = threadIdx.x >> 6, lane = threadIdx.x & 63;
  int lm = lane & 15, quad = lane >> 4;
  short8 bhf[2][3], blf[2][3];
  float bias0[2];
  if (bf16) {
    const unsigned short* W = (const unsigned short*)wgtv;
    for (int h = 0; h < 2; ++h)
      for (int g = 0; g < 3; ++g) {
        short8 vh, vl;
        #pragma unroll
        for (int j = 0; j < 8; ++j) {
          float w = bf2f(W[(g * CC + quad * 8 + j) * CC + h * 16 + lm]);
          unsigned short hi = f2bf(w);
          vh[j] = (short)hi;
          vl[j] = (short)f2bf(w - bf2f(hi));
        }
        bhf[h][g] = vh; blf[h][g] = vl;
      }
    for (int h = 0; h < 2; ++h) bias0[h] = bf2f(((const unsigned short*)biasv)[h * 16 + lm]);
  } else {
    const float* W = (const float*)wgtv;
    for (int h = 0; h < 2; ++h)
      for (int g = 0; g < 3; ++g) {
        short8 vh, vl;
        #pragma unroll
        for (int j = 0; j < 8; ++j) {
          float w = W[(g * CC + quad * 8 + j) * CC + h * 16 + lm];
          unsigned short hi = f2bf(w);
          vh[j] = (short)hi;
          vl[j] = (short)f2bf(w - bf2f(hi));
        }
        bhf[h][g] = vh; blf[h][g] = vl;
      }
    for (int h = 0; h < 2; ++h) bias0[h] = ((const float*)biasv)[h * 16 + lm];
  }
  int n0 = blockIdx.x * 4;
  #pragma unroll
  for (int tI = 0; tI < 3; ++tI) {
    int r0l = wid * BT + tI * 16;
    size_t abase = ((size_t)(n0 * BT) + r0l + lm) * CC + quad * 8;
    short8 af0 = *(const short8*)(H + abase);
    short8 af1 = *(const short8*)(T1 + abase);
    short8 af2 = *(const short8*)(T2 + abase);
    #pragma unroll
    for (int h = 0; h < 2; ++h) {
      f32x4 acc = {bias0[h], bias0[h], bias0[h], bias0[h]};
      acc = __builtin_amdgcn_mfma_f32_16x16x32_bf16(af0, bhf[h][0], acc, 0, 0, 0);
      acc = __builtin_amdgcn_mfma_f32_16x16x32_bf16(af0, blf[h][0], acc, 0, 0, 0);
      acc = __builtin_amdgcn_mfma_f32_16x16x32_bf16(af1, bhf[h][1], acc, 0, 0, 0);
      acc = __builtin_amdgcn_mfma_f32_16x16x32_bf16(af1, blf[h][1], acc, 0, 0, 0);
      acc = __builtin_amdgcn_mfma_f32_16x16x32_bf16(af2, bhf[h][2], acc, 0, 0, 0);
      acc = __builtin_amdgcn_mfma_f32_16x16x32_bf16(af2, blf[h][2], acc, 0, 0, 0);
      int o = h * 16 + lm;
      #pragma unroll
      for (int reg = 0; reg < 4; ++reg)
        sOut[(r0l + quad * 4 + reg) * SOP + o] = acc[reg];
    }
  }
  __syncthreads();
  #pragma unroll
  for (int j = 0; j < 6; ++j) {
    int idx = j * 256 + threadIdx.x;
    int bo = idx / 12;
    int fq = idx - bo * 12;
    int b = bo >> 5, o = bo & 31;
    int p0 = fq * 4;
    float v[4];
    #pragma unroll
    for (int k = 0; k < 4; ++k) {
      int p = p0 + k;
      int nl = p / TT, t = p - nl * TT;
      v[k] = sOut[(nl * BT + b * TT + t) * SOP + o];
    }
    size_t base = (((size_t)bo * NN) + n0) * TT + p0;
    if (bf16) {
      ushort4 s = {f2bf(v[0]), f2bf(v[1]), f2bf(v[2]), f2bf(v[3])};
      *(ushort4*)((unsigned short*)outv + base) = s;
    } else {
      *(float4*)((float*)outv + base) = make_float4(v[0], v[1], v[2], v[3]);
    }
  }
}

extern "C" void kernel_launch(void* const* d_in, const int* in_sizes, int n_in,
                              void* d_out, int out_size, void* d_ws, size_t ws_size,
                              hipStream_t stream) {
  const void* x    = d_in[0];
  const void* adj  = d_in[1];
  const void* wgt  = d_in[2];
  const void* bias = d_in[3];
  char* ws = (char*)d_ws;
  float* dis  = (float*)ws;                                 // 16 KB
  int*   deg  = (int*)(ws + 16384);                         // 16 KB
  uint2* edges = (uint2*)(ws + 32768);                      // 6.29 MB
  char* p = ws + 32768 + (size_t)NN * MAXD * 8;
  unsigned short* H  = (unsigned short*)p;                  // 12.58 MB
  unsigned short* T1 = (unsigned short*)(p + (size_t)NN * NC * 2);
  unsigned short* T2 = (unsigned short*)(p + (size_t)NN * NC * 4);

  k_build<<<NN, 256, 0, stream>>>(adj, wgt, edges, deg, dis);
  k_wt<<<NN, 192, 0, stream>>>(edges, deg, dis);
  k_trans<<<256, 256, 0, stream>>>(x, wgt, H);
  k_gather1<<<dim3(NN / 4, NCH), 256, 0, stream>>>(H, edges, deg, dis, T1);
  k_gather2<<<dim3(NN / 4, NCH), 256, 0, stream>>>(H, T1, edges, deg, dis, T2);
  k_mix<<<NN / 4, 256, 0, stream>>>(H, T1, T2, wgt, bias, d_out);
}

// Round 7
// 273.001 us; speedup vs baseline: 1.0832x; 1.0832x over previous
//
#include <hip/hip_runtime.h>

#define NN 4096
#define CC 32
#define TT 12
#define BB 4
#define BT 48          // BB*TT
#define NC 1536        // BT*CC
#define MAXD 192       // mean degree ~82; P(deg>192) astronomically small
#define FW 256         // features per chunk (4/lane, 8B); chunk slice = 4096*512B = 2MB (L2-resident)
#define NCH 6          // NC / FW
#define STP 36         // k_trans LDS row stride (ushorts)
#define SOP 33         // k_mix LDS row stride (floats)

typedef float f32x4 __attribute__((ext_vector_type(4)));
typedef short short8 __attribute__((ext_vector_type(8)));

__device__ __forceinline__ float bf2f(unsigned short h) {
  return __uint_as_float(((unsigned int)h) << 16);
}
__device__ __forceinline__ unsigned short f2bf(float f) {
  unsigned int u = __float_as_uint(f);
  return (unsigned short)((u + 0x7FFFu + ((u >> 16) & 1u)) >> 16);  // RNE
}
__device__ __forceinline__ float blo(unsigned int w) { return __uint_as_float(w << 16); }
__device__ __forceinline__ float bhi(unsigned int w) { return __uint_as_float(w & 0xFFFF0000u); }

// ---- adjacency (fp32) compaction into edges[].x + degree + d^-1/2
__global__ __launch_bounds__(256) void k_build(const float* __restrict__ adj,
                                               uint2* __restrict__ edges,
                                               int* __restrict__ deg, float* __restrict__ dis) {
  __shared__ int cnt;
  int m = blockIdx.x;
  if (threadIdx.x == 0) cnt = 0;
  __syncthreads();
  unsigned int* ecol = (unsigned int*)(edges + m * MAXD);
  const uint4* row = (const uint4*)(adj + (size_t)m * NN);
  for (int i = threadIdx.x; i < NN / 4; i += 256) {
    uint4 v = row[i];
    unsigned int ws[4] = {v.x, v.y, v.z, v.w};
    #pragma unroll
    for (int k = 0; k < 4; ++k) {
      if (ws[k] != 0) {
        int p = atomicAdd(&cnt, 1);
        if (p < MAXD) ecol[p * 2] = (unsigned int)(i * 4 + k);
      }
    }
  }
  __syncthreads();
  if (threadIdx.x == 0) {
    int d = cnt < MAXD ? cnt : MAXD;
    deg[m] = d;
    dis[m] = d > 0 ? (float)(1.0 / sqrt((double)d)) : 0.0f;
  }
}

// ---- edges[].y = dis[col]; pad edge list to multiple of 16 with {m, 0} dummies.
// Padded count goes to a SEPARATE array degp (no read/write race on deg).
__global__ __launch_bounds__(192) void k_wt(uint2* __restrict__ edges,
                                            const int* __restrict__ deg,
                                            int* __restrict__ degp,
                                            const float* __restrict__ dis) {
  int m = blockIdx.x;
  int j = threadIdx.x;
  int d = deg[m];
  int dp = (d + 15) & ~15;
  if (j < d) {
    unsigned int* e = (unsigned int*)(edges + m * MAXD + j);
    e[1] = __float_as_uint(dis[e[0]]);
  } else if (j < dp) {
    edges[m * MAXD + j] = make_uint2((unsigned int)m, 0u);  // weight 0.0f
  }
  if (j == 0) degp[m] = dp;
}

// ---- x[b][c][n][t] (fp32) -> H[n][bt][c] (bf16) via LDS transpose; coalesced both sides.
// Tile = 16 nodes x 1 b; grid = 4b x 256 tiles = 1024 blocks.
__global__ __launch_bounds__(256) void k_trans(const float* __restrict__ x,
                                               unsigned short* __restrict__ H) {
  __shared__ unsigned short sT[192 * STP];
  int b = blockIdx.x >> 8;
  int n0 = (blockIdx.x & 255) * 16;
  int c = threadIdx.x >> 3;        // 32 c-groups
  int l8 = threadIdx.x & 7;
  size_t base = ((size_t)(b * CC + c) * NN + n0) * TT;  // 192 contiguous floats per (b,c)
  #pragma unroll
  for (int it = 0; it < 6; ++it) {
    int j0 = it * 32 + l8 * 4;                 // j = nl*12 + t
    float4 f = *(const float4*)(x + base + j0);
    sT[(j0 + 0) * STP + c] = f2bf(f.x);
    sT[(j0 + 1) * STP + c] = f2bf(f.y);
    sT[(j0 + 2) * STP + c] = f2bf(f.z);
    sT[(j0 + 3) * STP + c] = f2bf(f.w);
  }
  __syncthreads();
  #pragma unroll
  for (int k = 0; k < 6; ++k) {
    int p = (threadIdx.x >> 3) + 32 * k;       // 192 (nl,t) runs
    int nl = p / TT, t = p - nl * TT;
    ushort4 v = *(const ushort4*)&sT[p * STP + l8 * 4];
    size_t off = ((size_t)(n0 + nl) * BT + b * TT + t) * CC + l8 * 4;
    *(ushort4*)(H + off) = v;
  }
}

// ---- gather1: T1[m,q] = H[m,q] - dis[m]*sum_e dis[col]*H[col,q]
// grid (NN/4, NCH); wave wid owns node bx*4+wid; 8B/lane covers 256 features.
// readfirstlane keeps edge stream provably wave-uniform -> batched s_loads.
__global__ __launch_bounds__(256) void k_gather1(const unsigned short* __restrict__ H,
                                                 const uint2* __restrict__ edges,
                                                 const int* __restrict__ degp,
                                                 const float* __restrict__ dis,
                                                 unsigned short* __restrict__ T1) {
  int wid = __builtin_amdgcn_readfirstlane(threadIdx.x >> 6);
  int lane = threadIdx.x & 63;
  int m = blockIdx.x * 4 + wid;
  int d = degp[m];                      // padded to x16
  float dm = dis[m];
  const uint2* ep = edges + m * MAXD;
  int fo = blockIdx.y * FW + lane * 4;
  const unsigned short* Hf = H + fo;
  float a0 = 0.f, a1 = 0.f, a2 = 0.f, a3 = 0.f;
  #pragma unroll 16
  for (int e = 0; e < d; ++e) {
    uint2 ew = ep[e];                   // wave-uniform
    int cc = (int)ew.x;
    float w = __uint_as_float(ew.y);
    uint2 hv = *(const uint2*)(Hf + cc * NC);
    a0 = fmaf(w, blo(hv.x), a0); a1 = fmaf(w, bhi(hv.x), a1);
    a2 = fmaf(w, blo(hv.y), a2); a3 = fmaf(w, bhi(hv.y), a3);
  }
  uint2 hm = *(const uint2*)(Hf + m * NC);
  ushort4 o;
  o.x = f2bf(blo(hm.x) - dm * a0); o.y = f2bf(bhi(hm.x) - dm * a1);
  o.z = f2bf(blo(hm.y) - dm * a2); o.w = f2bf(bhi(hm.y) - dm * a3);
  *(ushort4*)(T1 + (size_t)m * NC + fo) = o;
}

// ---- gather2: T2[m,q] = 2*T1[m,q] - 2*dm*sum_e dis[col]*T1[col,q] - H[m,q]
__global__ __launch_bounds__(256) void k_gather2(const unsigned short* __restrict__ H,
                                                 const unsigned short* __restrict__ T1,
                                                 const uint2* __restrict__ edges,
                                                 const int* __restrict__ degp,
                                                 const float* __restrict__ dis,
                                                 unsigned short* __restrict__ T2) {
  int wid = __builtin_amdgcn_readfirstlane(threadIdx.x >> 6);
  int lane = threadIdx.x & 63;
  int m = blockIdx.x * 4 + wid;
  int d = degp[m];
  float dm = dis[m];
  const uint2* ep = edges + m * MAXD;
  int fo = blockIdx.y * FW + lane * 4;
  const unsigned short* Tf = T1 + fo;
  float a0 = 0.f, a1 = 0.f, a2 = 0.f, a3 = 0.f;
  #pragma unroll 16
  for (int e = 0; e < d; ++e) {
    uint2 ew = ep[e];
    int cc = (int)ew.x;
    float w = __uint_as_float(ew.y);
    uint2 hv = *(const uint2*)(Tf + cc * NC);
    a0 = fmaf(w, blo(hv.x), a0); a1 = fmaf(w, bhi(hv.x), a1);
    a2 = fmaf(w, blo(hv.y), a2); a3 = fmaf(w, bhi(hv.y), a3);
  }
  uint2 tm = *(const uint2*)(Tf + m * NC);
  uint2 hm = *(const uint2*)(H + (size_t)m * NC + fo);
  float td = 2.f * dm;
  ushort4 o;
  o.x = f2bf(2.f * blo(tm.x) - td * a0 - blo(hm.x));
  o.y = f2bf(2.f * bhi(tm.x) - td * a1 - bhi(hm.x));
  o.z = f2bf(2.f * blo(tm.y) - td * a2 - blo(hm.y));
  o.w = f2bf(2.f * bhi(tm.y) - td * a3 - bhi(hm.y));
  *(ushort4*)(T2 + (size_t)m * NC + fo) = o;
}

// ---- MFMA channel mix: out = W0*H + W1*T1 + W2*T2 + bias -> [B,32,N,T] (fp32)
// Block = 4 nodes (192 rows); wave wid MFMAs node wid (3 tiles x 2 col-halves),
// C-frags -> padded LDS, barrier, coalesced float4 stores. W (fp32) split hi/lo bf16.
__global__ __launch_bounds__(256) void k_mix(const unsigned short* __restrict__ H,
                                             const unsigned short* __restrict__ T1,
                                             const unsigned short* __restrict__ T2,
                                             const float* __restrict__ W,
                                             const float* __restrict__ bias,
                                             float* __restrict__ out) {
  __shared__ __align__(16) float sOut[192 * SOP];
  int wid = threadIdx.x >> 6, lane = threadIdx.x & 63;
  int lm = lane & 15, quad = lane >> 4;
  short8 bhf[2][3], blf[2][3];
  float bias0[2];
  for (int h = 0; h < 2; ++h)
    for (int g = 0; g < 3; ++g) {
      short8 vh, vl;
      #pragma unroll
      for (int j = 0; j < 8; ++j) {
        float w = W[(g * CC + quad * 8 + j) * CC + h * 16 + lm];
        unsigned short hi = f2bf(w);
        vh[j] = (short)hi;
        vl[j] = (short)f2bf(w - bf2f(hi));
      }
      bhf[h][g] = vh; blf[h][g] = vl;
    }
  #pragma unroll
  for (int h = 0; h < 2; ++h) bias0[h] = bias[h * 16 + lm];
  int n0 = blockIdx.x * 4;
  #pragma unroll
  for (int tI = 0; tI < 3; ++tI) {
    int r0l = wid * BT + tI * 16;
    size_t abase = ((size_t)(n0 * BT) + r0l + lm) * CC + quad * 8;
    short8 af0 = *(const short8*)(H + abase);
    short8 af1 = *(const short8*)(T1 + abase);
    short8 af2 = *(const short8*)(T2 + abase);
    #pragma unroll
    for (int h = 0; h < 2; ++h) {
      f32x4 acc = {bias0[h], bias0[h], bias0[h], bias0[h]};
      acc = __builtin_amdgcn_mfma_f32_16x16x32_bf16(af0, bhf[h][0], acc, 0, 0, 0);
      acc = __builtin_amdgcn_mfma_f32_16x16x32_bf16(af0, blf[h][0], acc, 0, 0, 0);
      acc = __builtin_amdgcn_mfma_f32_16x16x32_bf16(af1, bhf[h][1], acc, 0, 0, 0);
      acc = __builtin_amdgcn_mfma_f32_16x16x32_bf16(af1, blf[h][1], acc, 0, 0, 0);
      acc = __builtin_amdgcn_mfma_f32_16x16x32_bf16(af2, bhf[h][2], acc, 0, 0, 0);
      acc = __builtin_amdgcn_mfma_f32_16x16x32_bf16(af2, blf[h][2], acc, 0, 0, 0);
      int o = h * 16 + lm;
      #pragma unroll
      for (int reg = 0; reg < 4; ++reg)
        sOut[(r0l + quad * 4 + reg) * SOP + o] = acc[reg];
    }
  }
  __syncthreads();
  #pragma unroll
  for (int j = 0; j < 6; ++j) {
    int idx = j * 256 + threadIdx.x;
    int bo = idx / 12;                  // b*32 + o
    int fq = idx - bo * 12;
    int p0 = fq * 4;                    // elem within the 48-long (b,o) run
    float v[4];
    #pragma unroll
    for (int k = 0; k < 4; ++k) {
      int p = p0 + k;
      int nl = p / TT, t = p - nl * TT;
      int b = bo >> 5, o = bo & 31;
      v[k] = sOut[(nl * BT + b * TT + t) * SOP + o];
    }
    size_t base = (((size_t)bo * NN) + n0) * TT + p0;
    *(float4*)(out + base) = make_float4(v[0], v[1], v[2], v[3]);
  }
}

extern "C" void kernel_launch(void* const* d_in, const int* in_sizes, int n_in,
                              void* d_out, int out_size, void* d_ws, size_t ws_size,
                              hipStream_t stream) {
  const float* x    = (const float*)d_in[0];
  const float* adj  = (const float*)d_in[1];
  const float* wgt  = (const float*)d_in[2];
  const float* bias = (const float*)d_in[3];
  char* ws = (char*)d_ws;
  float* dis  = (float*)ws;                                 // 16 KB
  int*   deg  = (int*)(ws + 16384);                         // 16 KB
  int*   degp = (int*)(ws + 32768);                         // 16 KB
  uint2* edges = (uint2*)(ws + 49152);                      // 6.29 MB
  char* p = ws + 49152 + (size_t)NN * MAXD * 8;
  unsigned short* H  = (unsigned short*)p;                  // 12.58 MB
  unsigned short* T1 = (unsigned short*)(p + (size_t)NN * NC * 2);
  unsigned short* T2 = (unsigned short*)(p + (size_t)NN * NC * 4);

  k_build<<<NN, 256, 0, stream>>>(adj, edges, deg, dis);
  k_wt<<<NN, 192, 0, stream>>>(edges, deg, degp, dis);
  k_trans<<<1024, 256, 0, stream>>>(x, H);
  k_gather1<<<dim3(NN / 4, NCH), 256, 0, stream>>>(H, edges, degp, dis, T1);
  k_gather2<<<dim3(NN / 4, NCH), 256, 0, stream>>>(H, T1, edges, degp, dis, T2);
  k_mix<<<NN / 4, 256, 0, stream>>>(H, T1, T2, wgt, bias, (float*)d_out);
}